// Round 9
// baseline (240.962 us; speedup 1.0000x reference)
//
#include <hip/hip_runtime.h>

#define N_NODES 50000
#define N_EDGES 800000
#define D0 256
#define D1 128
#define D2 32
#define CAP 48             // bucket capacity per row (max degree ~36; P(>48) ~ 8-sigma)
#define NB 391             // row-buckets of 128 rows: ceil(50000/128)
#define BCAP 3072          // u64 slots per bucket region (expected ~2046/bucket; +22 sigma)
#define EB 8192            // edges per scatter block (8/thread @ 1024 threads)
#define SC_BLOCKS 98       // ceil(800000/8192)
#define SW_BLOCKS 4        // W1 swizzle: 4096 threads = 4 x 1024
#define G1_BLOCKS 782      // ceil(50000/64)
#define RG_BLOCKS 1563     // ceil(50000/32) row-groups for the sliced spmm1
#define PL ((size_t)N_NODES * 16)   // u16 elements per s1b slice plane (1.6 MB)

typedef unsigned short u16;
typedef unsigned int   u32;
typedef unsigned long long u64;
typedef __attribute__((ext_vector_type(8))) short bf16x8;
typedef __attribute__((ext_vector_type(4))) float f32x4;

__device__ inline u32 bf16rne(float f) {
    union { float f; u32 u; } c; c.f = f;
    return (c.u + 0x7FFFu + ((c.u >> 16) & 1u)) >> 16;
}
__device__ inline float bfhi(u32 v) {      // high 16 bits hold the bf16
    union { u32 u; float f; } c; c.u = v & 0xFFFF0000u; return c.f;
}
__device__ inline float bflo(u32 v) {      // low 16 bits hold the bf16
    union { u32 u; float f; } c; c.u = v << 16; return c.f;
}
// nontemporal uint4 load (two nt u64 loads; keeps streamed eg out of L2)
__device__ inline uint4 nt_load_u4(const u32* p) {
    const u64* q = (const u64*)p;
    const u64 a = __builtin_nontemporal_load(q);
    const u64 b = __builtin_nontemporal_load(q + 1);
    uint4 r; r.x = (u32)a; r.y = (u32)(a >> 32); r.z = (u32)b; r.w = (u32)(b >> 32);
    return r;
}

// ==== k1: bucket-sort phase 1 (scatter) | W1 swizzle | W2 swizzle ===============
__global__ __launch_bounds__(1024) void scatter_kernel(const int* __restrict__ erow,
                                                       const int* __restrict__ ecol,
                                                       const float* __restrict__ ew,
                                                       u32* __restrict__ bcur,
                                                       u64* __restrict__ ebuf,
                                                       const float* __restrict__ W1,
                                                       u16* __restrict__ Bsw1,
                                                       const float* __restrict__ W2,
                                                       u16* __restrict__ Bsw2) {
    __shared__ u32 hist[NB];
    __shared__ u32 lbase[NB];
    const int tid = threadIdx.x;
    if (blockIdx.x < SC_BLOCKS) {
        if (tid < NB) hist[tid] = 0;
        __syncthreads();
        const int ebase = blockIdx.x * EB;
        #pragma unroll
        for (int k = 0; k < EB / 1024; ++k) {
            const int e = ebase + k * 1024 + tid;
            if (e < N_EDGES) atomicAdd(&hist[erow[e] >> 7], 1u);
        }
        __syncthreads();
        if (tid < NB) {
            const u32 h = hist[tid];
            lbase[tid] = h ? atomicAdd(&bcur[tid], h) : 0u;
            hist[tid] = 0;                   // reuse as local cursor
        }
        __syncthreads();
        #pragma unroll
        for (int k = 0; k < EB / 1024; ++k) {
            const int e = ebase + k * 1024 + tid;
            if (e < N_EDGES) {
                const int r = erow[e];
                const int c = ecol[e];
                const float w = ew[e];
                const int b = r >> 7;
                const u32 lr = atomicAdd(&hist[b], 1u);
                const u32 pos = lbase[b] + lr;
                if (pos < BCAP)              // deterministically never taken; guards memory
                    ebuf[(size_t)b * BCAP + pos] =
                        (u64)(u32)c | ((u64)(u32)(r & 127) << 16) | ((u64)bf16rne(w) << 32);
            }
        }
    } else if (blockIdx.x < SC_BLOCKS + SW_BLOCKS) {
        // ---- W1 fragment swizzle (K=256, N=128): 4096 ids ----
        const int id = (blockIdx.x - SC_BLOCKS) * 1024 + tid;   // 0..4095
        const int lane = id & 63;
        const int t    = (id >> 6) & 7;
        const int ks   = id >> 9;
        const int n     = t * 16 + (lane & 15);
        const int kbase = ks * 32 + (lane >> 4) * 8;
        u32 v[8];
        #pragma unroll
        for (int j = 0; j < 8; ++j) v[j] = bf16rne(W1[(kbase + j) * D1 + n]);
        uint4 w;
        w.x = v[0] | (v[1] << 16);
        w.y = v[2] | (v[3] << 16);
        w.z = v[4] | (v[5] << 16);
        w.w = v[6] | (v[7] << 16);
        ((uint4*)Bsw1)[id] = w;
    } else if (tid < 512) {
        // ---- W2 fragment swizzle (K=128, N=32): 512 ids ----
        const int id = tid;
        const int lane = id & 63;
        const int t    = (id >> 6) & 1;
        const int ks   = id >> 7;
        const int n     = t * 16 + (lane & 15);
        const int kbase = ks * 32 + (lane >> 4) * 8;
        u32 v[8];
        #pragma unroll
        for (int j = 0; j < 8; ++j) v[j] = bf16rne(W2[(kbase + j) * D2 + n]);
        uint4 w;
        w.x = v[0] | (v[1] << 16);
        w.y = v[2] | (v[3] << 16);
        w.z = v[4] | (v[5] << 16);
        w.w = v[6] | (v[7] << 16);
        ((uint4*)Bsw2)[id] = w;
    }
}

// ================= k2: fused  bucket-sort phase 2 | gemm1(MFMA) =================
// gemm1 now writes s1b SLICE-MAJOR: plane t holds features [t*16, t*16+16) for all
// rows ([N_NODES][16] = 1.6MB/plane). Feature f = t*16+m -> plane t, offset m, so
// the 8 existing scattered u16 stores just re-target; store count unchanged.
__global__ __launch_bounds__(256) void gb_kernel(const float* __restrict__ x,
                                                 const u16* __restrict__ Bsw1,
                                                 u16* __restrict__ s1b,
                                                 const u32* __restrict__ bcur,
                                                 const u64* __restrict__ ebuf,
                                                 int* __restrict__ cnt,
                                                 u32* __restrict__ eg) {
    __shared__ u32 seg[128 * CAP];           // 24 KB (bucket branch only)
    __shared__ u32 lcnt[128];
    const int bid = blockIdx.x;
    if (bid < NB) {
        const int b = bid;
        for (int i = threadIdx.x; i < 128; i += 256) lcnt[i] = 0;
        __syncthreads();
        int n = (int)bcur[b];                // edges landed in this bucket (~2046)
        if (n > BCAP) n = BCAP;              // defensive clamp
        const u64* ep = ebuf + (size_t)b * BCAP;
        for (int i = threadIdx.x; i < n; i += 256) {
            const u64 e = __builtin_nontemporal_load(ep + i);   // pure stream
            const u32 c  = (u32)(e & 0xFFFFu);
            const u32 lr = (u32)((e >> 16) & 0x7Fu);
            const u32 w  = (u32)(e >> 32);
            const u32 p = atomicAdd(&lcnt[lr], 1u);
            if (p < CAP)                     // max degree ~36; guards LDS
                seg[lr * CAP + p] = c | (w << 16);
        }
        __syncthreads();
        const int rows = min(128, N_NODES - b * 128);
        for (int i = threadIdx.x; i < rows; i += 256)
            cnt[b * 128 + i] = (int)min(lcnt[i], (u32)CAP);
        u32* dst = eg + (size_t)b * 128 * CAP;
        const int nvec = rows * (CAP / 4);   // uint4 count (rows*12)
        for (int i = threadIdx.x; i < nvec; i += 256)
            ((uint4*)dst)[i] = ((const uint4*)seg)[i];
    } else {
        // ---- gemm1: s1b(slice-major) = bf16(x[N,256]) @ W1 ----
        const int gb   = bid - NB;
        const int lane = threadIdx.x & 63;
        const int wave = threadIdx.x >> 6;
        const int rowbase = gb * 64 + wave * 16;
        const int m    = lane & 15;
        const int quad = lane >> 4;
        int arow = rowbase + m;
        if (arow >= N_NODES) arow = N_NODES - 1;
        const float* aptr = x + (size_t)arow * D0 + quad * 8;

        f32x4 acc[8];
        #pragma unroll
        for (int t = 0; t < 8; ++t) acc[t] = (f32x4){0.f, 0.f, 0.f, 0.f};

        #pragma unroll
        for (int ks = 0; ks < 8; ++ks) {
            const float4 f0 = *(const float4*)(aptr + ks * 32);
            const float4 f1 = *(const float4*)(aptr + ks * 32 + 4);
            bf16x8 a;
            a[0] = (short)bf16rne(f0.x); a[1] = (short)bf16rne(f0.y);
            a[2] = (short)bf16rne(f0.z); a[3] = (short)bf16rne(f0.w);
            a[4] = (short)bf16rne(f1.x); a[5] = (short)bf16rne(f1.y);
            a[6] = (short)bf16rne(f1.z); a[7] = (short)bf16rne(f1.w);
            const u16* bp = Bsw1 + ((size_t)(ks * 8) * 64 + lane) * 8;
            #pragma unroll
            for (int t = 0; t < 8; ++t) {
                const bf16x8 b = *(const bf16x8*)(bp + (size_t)t * 64 * 8);
                acc[t] = __builtin_amdgcn_mfma_f32_16x16x32_bf16(a, b, acc[t], 0, 0, 0);
            }
        }
        const int orow = rowbase + quad * 4;
        #pragma unroll
        for (int r = 0; r < 4; ++r) {
            const int row = orow + r;
            if (row < N_NODES) {
                #pragma unroll
                for (int t = 0; t < 8; ++t)
                    s1b[(size_t)t * PL + (size_t)row * 16 + m] = (u16)bf16rne(acc[t][r]);
            }
        }
    }
}

// ====== k3: XCD-sliced spmm1: hb[N,128](bf16) = relu(A @ s1b + b1) ==============
// slice = bid & 7 == XCD (round-robin dispatch). Plane s is [N_NODES][16] = 1.6MB
// CONTIGUOUS (round-8's fatal flaw: 32B slices interleaved in 256B rows made the
// line-granular working set 6.4MB/XCD -> thrash, FETCH 248MB). eg is nt-streamed
// so it can't evict the resident plane; hb stores are nt (consumed next kernel).
__global__ __launch_bounds__(256) void spmm1_slice_kernel(const int* __restrict__ cnt,
                                                          const u32* __restrict__ eg,
                                                          const u16* __restrict__ src,
                                                          const float* __restrict__ b1,
                                                          u16* __restrict__ hb) {
    const int tx = threadIdx.x;                        // 0..7 (feature pair)
    const int s  = blockIdx.x & 7;                     // slice == XCD
    const int rg = blockIdx.x >> 3;
    const int row = rg * 32 + threadIdx.y;
    if (row >= N_NODES) return;
    int len = cnt[row];
    if (len > CAP) len = CAP;
    const u32* ep = eg + (size_t)row * CAP;
    const u16* sp = src + (size_t)s * PL;              // slice plane base
    float ax0=0.f, ay0=0.f, ax1=0.f, ay1=0.f, ax2=0.f, ay2=0.f, ax3=0.f, ay3=0.f;
    int j = 0;
    for (; j + 7 < len; j += 8) {                      // 8 gathers in flight
        const uint4 e4a = nt_load_u4(ep + j);
        const uint4 e4b = nt_load_u4(ep + j + 4);
        const u32 v0 = ((const u32*)(sp + (size_t)(e4a.x & 0xFFFFu) * 16))[tx];
        const u32 v1 = ((const u32*)(sp + (size_t)(e4a.y & 0xFFFFu) * 16))[tx];
        const u32 v2 = ((const u32*)(sp + (size_t)(e4a.z & 0xFFFFu) * 16))[tx];
        const u32 v3 = ((const u32*)(sp + (size_t)(e4a.w & 0xFFFFu) * 16))[tx];
        const u32 v4 = ((const u32*)(sp + (size_t)(e4b.x & 0xFFFFu) * 16))[tx];
        const u32 v5 = ((const u32*)(sp + (size_t)(e4b.y & 0xFFFFu) * 16))[tx];
        const u32 v6 = ((const u32*)(sp + (size_t)(e4b.z & 0xFFFFu) * 16))[tx];
        const u32 v7 = ((const u32*)(sp + (size_t)(e4b.w & 0xFFFFu) * 16))[tx];
        const float w0 = bfhi(e4a.x), w1 = bfhi(e4a.y), w2 = bfhi(e4a.z), w3 = bfhi(e4a.w);
        const float w4 = bfhi(e4b.x), w5 = bfhi(e4b.y), w6 = bfhi(e4b.z), w7 = bfhi(e4b.w);
        ax0 += w0 * bflo(v0); ay0 += w0 * bfhi(v0);
        ax1 += w1 * bflo(v1); ay1 += w1 * bfhi(v1);
        ax2 += w2 * bflo(v2); ay2 += w2 * bfhi(v2);
        ax3 += w3 * bflo(v3); ay3 += w3 * bfhi(v3);
        ax0 += w4 * bflo(v4); ay0 += w4 * bfhi(v4);
        ax1 += w5 * bflo(v5); ay1 += w5 * bfhi(v5);
        ax2 += w6 * bflo(v6); ay2 += w6 * bfhi(v6);
        ax3 += w7 * bflo(v7); ay3 += w7 * bfhi(v7);
    }
    for (; j + 3 < len; j += 4) {
        const uint4 e4 = nt_load_u4(ep + j);
        const u32 v0 = ((const u32*)(sp + (size_t)(e4.x & 0xFFFFu) * 16))[tx];
        const u32 v1 = ((const u32*)(sp + (size_t)(e4.y & 0xFFFFu) * 16))[tx];
        const u32 v2 = ((const u32*)(sp + (size_t)(e4.z & 0xFFFFu) * 16))[tx];
        const u32 v3 = ((const u32*)(sp + (size_t)(e4.w & 0xFFFFu) * 16))[tx];
        const float w0 = bfhi(e4.x), w1 = bfhi(e4.y), w2 = bfhi(e4.z), w3 = bfhi(e4.w);
        ax0 += w0 * bflo(v0); ay0 += w0 * bfhi(v0);
        ax1 += w1 * bflo(v1); ay1 += w1 * bfhi(v1);
        ax2 += w2 * bflo(v2); ay2 += w2 * bfhi(v2);
        ax3 += w3 * bflo(v3); ay3 += w3 * bfhi(v3);
    }
    for (; j < len; ++j) {
        const u32 e0 = __builtin_nontemporal_load(ep + j);
        const u32 v0 = ((const u32*)(sp + (size_t)(e0 & 0xFFFFu) * 16))[tx];
        const float w0 = bfhi(e0);
        ax0 += w0 * bflo(v0); ay0 += w0 * bfhi(v0);
    }
    const float2 bv = ((const float2*)(b1 + s * 16))[tx];
    float vx = ax0 + ax1 + ax2 + ax3 + bv.x; vx = vx > 0.f ? vx : 0.f;
    float vy = ay0 + ay1 + ay2 + ay3 + bv.y; vy = vy > 0.f ? vy : 0.f;
    __builtin_nontemporal_store(bf16rne(vx) | (bf16rne(vy) << 16),
                                (u32*)(hb + (size_t)row * D1 + s * 16) + tx);
}

// ================= gemm2 MFMA: s2b[N,32](bf16) = hb[N,128] @ W2 =================
__global__ __launch_bounds__(256) void gemm2_mfma_kernel(const u16* __restrict__ hb,
                                                         const u16* __restrict__ Bsw2,
                                                         u16* __restrict__ s2b) {
    const int lane = threadIdx.x & 63;
    const int wave = threadIdx.x >> 6;
    const int rowbase = blockIdx.x * 64 + wave * 16;
    const int m    = lane & 15;
    const int quad = lane >> 4;
    int arow = rowbase + m;
    if (arow >= N_NODES) arow = N_NODES - 1;
    const u16* aptr = hb + (size_t)arow * D1 + quad * 8;

    f32x4 acc0 = (f32x4){0.f,0.f,0.f,0.f};
    f32x4 acc1 = (f32x4){0.f,0.f,0.f,0.f};

    #pragma unroll
    for (int ks = 0; ks < 4; ++ks) {
        const bf16x8 a = *(const bf16x8*)(aptr + ks * 32);
        const u16* bp = Bsw2 + ((size_t)(ks * 2) * 64 + lane) * 8;
        const bf16x8 b0 = *(const bf16x8*)(bp);
        const bf16x8 b1 = *(const bf16x8*)(bp + (size_t)64 * 8);
        acc0 = __builtin_amdgcn_mfma_f32_16x16x32_bf16(a, b0, acc0, 0, 0, 0);
        acc1 = __builtin_amdgcn_mfma_f32_16x16x32_bf16(a, b1, acc1, 0, 0, 0);
    }
    const int orow = rowbase + quad * 4;
    #pragma unroll
    for (int r = 0; r < 4; ++r) {
        const int row = orow + r;
        if (row < N_NODES) {
            u16* op = s2b + (size_t)row * D2 + m;
            op[0]  = (u16)bf16rne(acc0[r]);
            op[16] = (u16)bf16rne(acc1[r]);
        }
    }
}

// ================= spmm2: out[N,32](f32) = relu(A @ s2b + b2) ===================
// s2b table = 3.2MB < 4MB per-XCD L2: resident once eg is nt-streamed around it.
__global__ __launch_bounds__(256) void spmm_csr32_kernel(const int* __restrict__ cnt,
                                                         const u32* __restrict__ eg,
                                                         const u16* __restrict__ src,
                                                         const float* __restrict__ bias,
                                                         float* __restrict__ out) {
    const int lane = threadIdx.x;                      // 0..15
    const int row  = blockIdx.x * 16 + threadIdx.y;
    if (row >= N_NODES) return;
    int len = cnt[row];
    if (len > CAP) len = CAP;
    const u32* ep = eg + (size_t)row * CAP;
    float ax0=0.f, ay0=0.f, ax1=0.f, ay1=0.f, ax2=0.f, ay2=0.f, ax3=0.f, ay3=0.f;
    int j = 0;
    for (; j + 7 < len; j += 8) {                      // 8 loads in flight
        const uint4 e4a = nt_load_u4(ep + j);
        const uint4 e4b = nt_load_u4(ep + j + 4);
        const u32 v0 = ((const u32*)(src + (size_t)(e4a.x & 0xFFFFu) * D2))[lane];
        const u32 v1 = ((const u32*)(src + (size_t)(e4a.y & 0xFFFFu) * D2))[lane];
        const u32 v2 = ((const u32*)(src + (size_t)(e4a.z & 0xFFFFu) * D2))[lane];
        const u32 v3 = ((const u32*)(src + (size_t)(e4a.w & 0xFFFFu) * D2))[lane];
        const u32 v4 = ((const u32*)(src + (size_t)(e4b.x & 0xFFFFu) * D2))[lane];
        const u32 v5 = ((const u32*)(src + (size_t)(e4b.y & 0xFFFFu) * D2))[lane];
        const u32 v6 = ((const u32*)(src + (size_t)(e4b.z & 0xFFFFu) * D2))[lane];
        const u32 v7 = ((const u32*)(src + (size_t)(e4b.w & 0xFFFFu) * D2))[lane];
        const float w0 = bfhi(e4a.x), w1 = bfhi(e4a.y), w2 = bfhi(e4a.z), w3 = bfhi(e4a.w);
        const float w4 = bfhi(e4b.x), w5 = bfhi(e4b.y), w6 = bfhi(e4b.z), w7 = bfhi(e4b.w);
        ax0 += w0 * bflo(v0); ay0 += w0 * bfhi(v0);
        ax1 += w1 * bflo(v1); ay1 += w1 * bfhi(v1);
        ax2 += w2 * bflo(v2); ay2 += w2 * bfhi(v2);
        ax3 += w3 * bflo(v3); ay3 += w3 * bfhi(v3);
        ax0 += w4 * bflo(v4); ay0 += w4 * bfhi(v4);
        ax1 += w5 * bflo(v5); ay1 += w5 * bfhi(v5);
        ax2 += w6 * bflo(v6); ay2 += w6 * bfhi(v6);
        ax3 += w7 * bflo(v7); ay3 += w7 * bfhi(v7);
    }
    for (; j + 3 < len; j += 4) {
        const uint4 e4 = nt_load_u4(ep + j);
        const u32 v0 = ((const u32*)(src + (size_t)(e4.x & 0xFFFFu) * D2))[lane];
        const u32 v1 = ((const u32*)(src + (size_t)(e4.y & 0xFFFFu) * D2))[lane];
        const u32 v2 = ((const u32*)(src + (size_t)(e4.z & 0xFFFFu) * D2))[lane];
        const u32 v3 = ((const u32*)(src + (size_t)(e4.w & 0xFFFFu) * D2))[lane];
        const float w0 = bfhi(e4.x), w1 = bfhi(e4.y), w2 = bfhi(e4.z), w3 = bfhi(e4.w);
        ax0 += w0 * bflo(v0); ay0 += w0 * bfhi(v0);
        ax1 += w1 * bflo(v1); ay1 += w1 * bfhi(v1);
        ax2 += w2 * bflo(v2); ay2 += w2 * bfhi(v2);
        ax3 += w3 * bflo(v3); ay3 += w3 * bfhi(v3);
    }
    for (; j < len; ++j) {
        const u32 e0 = __builtin_nontemporal_load(ep + j);
        const u32 v0 = ((const u32*)(src + (size_t)(e0 & 0xFFFFu) * D2))[lane];
        const float w0 = bfhi(e0);
        ax0 += w0 * bflo(v0); ay0 += w0 * bfhi(v0);
    }
    const float2 b2v = ((const float2*)bias)[lane];
    float vx = ax0 + ax1 + ax2 + ax3 + b2v.x; vx = vx > 0.f ? vx : 0.f;
    float vy = ay0 + ay1 + ay2 + ay3 + b2v.y; vy = vy > 0.f ? vy : 0.f;
    union { float2 f; u64 u; } o; o.f = make_float2(vx, vy);
    __builtin_nontemporal_store(o.u, (u64*)(out + (size_t)row * D2) + lane);
}

extern "C" void kernel_launch(void* const* d_in, const int* in_sizes, int n_in,
                              void* d_out, int out_size, void* d_ws, size_t ws_size,
                              hipStream_t stream) {
    const float* x    = (const float*)d_in[0];
    const int*   erow = (const int*)  d_in[1];
    const int*   ecol = (const int*)  d_in[2];
    const float* ew   = (const float*)d_in[3];
    const float* W1   = (const float*)d_in[4];
    const float* b1   = (const float*)d_in[5];
    const float* W2   = (const float*)d_in[6];
    const float* b2   = (const float*)d_in[7];
    float* out = (float*)d_out;

    // workspace layout (~49 MB, no aliasing):
    //   cnt[N int]  bcur[512 u32]  eg[N*CAP u32]  Bsw1[32768 u16]  Bsw2[4096 u16]
    //   s1b[8 planes x N*16 u16]  hb[N*128 u16]  s2b[N*32 u16]  ebuf[NB*BCAP u64]
    int* cnt   = (int*)d_ws;
    u32* bcur  = (u32*)(cnt + N_NODES);
    u32* eg    = (u32*)(bcur + 512);
    u16* Bsw1  = (u16*)(eg + (size_t)N_NODES * CAP);
    u16* Bsw2  = Bsw1 + 8 * 8 * 64 * 8;
    u16* s1b   = Bsw2 + 4 * 2 * 64 * 8;
    u16* hb    = s1b + 8 * PL;
    u16* s2b   = hb + (size_t)N_NODES * D1;
    u64* ebuf  = (u64*)(s2b + (size_t)N_NODES * D2);

    hipMemsetAsync(bcur, 0, 512 * sizeof(u32), stream);
    // k1: bucket-sort phase 1 (scatter) | W1 swizzle | W2 swizzle
    scatter_kernel<<<SC_BLOCKS + SW_BLOCKS + 1, 1024, 0, stream>>>(
        erow, ecol, ew, bcur, ebuf, W1, Bsw1, W2, Bsw2);
    // k2: bucket-sort phase 2 | gemm1 (slice-major s1b)
    gb_kernel<<<NB + G1_BLOCKS, 256, 0, stream>>>(x, Bsw1, s1b, bcur, ebuf, cnt, eg);
    // k3: XCD-sliced layer-1 aggregate (slice = bid&7 == XCD; 1.6MB L2-resident plane)
    spmm1_slice_kernel<<<RG_BLOCKS * 8, dim3(8, 32), 0, stream>>>(cnt, eg, s1b, b1, hb);
    // k4: layer-2 dense projection (MFMA)
    gemm2_mfma_kernel<<<(N_NODES + 63) / 64, 256, 0, stream>>>(hb, Bsw2, s2b);
    // k5: layer-2 aggregate
    spmm_csr32_kernel<<<(N_NODES + 15) / 16, dim3(16, 16), 0, stream>>>(cnt, eg, s2b, b2, out);
}

// Round 10
// 197.547 us; speedup vs baseline: 1.2198x; 1.2198x over previous
//
#include <hip/hip_runtime.h>

#define N_NODES 50000
#define N_EDGES 800000
#define D0 256
#define D1 128
#define D2 32
#define CAP 48             // bucket capacity per row (max degree ~36; P(>48) ~ 8-sigma)
#define NB 391             // row-buckets of 128 rows: ceil(50000/128)
#define BCAP 3072          // u64 slots per bucket region (expected ~2046/bucket; +22 sigma)
#define EB 8192            // edges per scatter block (8/thread @ 1024 threads)
#define SC_BLOCKS 98       // ceil(800000/8192)
#define SW_BLOCKS 4        // W1 swizzle: 4096 threads = 4 x 1024
#define G1_BLOCKS 782      // ceil(50000/64)
#define RG_BLOCKS 1563     // ceil(50000/32) row-groups for the sliced spmm1
#define PL ((size_t)N_NODES * 16)   // u16 elements per s1b slice plane (1.6 MB)

typedef unsigned short u16;
typedef unsigned int   u32;
typedef unsigned long long u64;
typedef __attribute__((ext_vector_type(8))) short bf16x8;
typedef __attribute__((ext_vector_type(4))) float f32x4;

__device__ inline u32 bf16rne(float f) {
    union { float f; u32 u; } c; c.f = f;
    return (c.u + 0x7FFFu + ((c.u >> 16) & 1u)) >> 16;
}
__device__ inline float bfhi(u32 v) {      // high 16 bits hold the bf16
    union { u32 u; float f; } c; c.u = v & 0xFFFF0000u; return c.f;
}
__device__ inline float bflo(u32 v) {      // low 16 bits hold the bf16
    union { u32 u; float f; } c; c.u = v << 16; return c.f;
}

// ==== k1: bucket-sort phase 1 (scatter) | W1 swizzle | W2 swizzle ===============
__global__ __launch_bounds__(1024) void scatter_kernel(const int* __restrict__ erow,
                                                       const int* __restrict__ ecol,
                                                       const float* __restrict__ ew,
                                                       u32* __restrict__ bcur,
                                                       u64* __restrict__ ebuf,
                                                       const float* __restrict__ W1,
                                                       u16* __restrict__ Bsw1,
                                                       const float* __restrict__ W2,
                                                       u16* __restrict__ Bsw2) {
    __shared__ u32 hist[NB];
    __shared__ u32 lbase[NB];
    const int tid = threadIdx.x;
    if (blockIdx.x < SC_BLOCKS) {
        if (tid < NB) hist[tid] = 0;
        __syncthreads();
        const int ebase = blockIdx.x * EB;
        #pragma unroll
        for (int k = 0; k < EB / 1024; ++k) {
            const int e = ebase + k * 1024 + tid;
            if (e < N_EDGES) atomicAdd(&hist[erow[e] >> 7], 1u);
        }
        __syncthreads();
        if (tid < NB) {
            const u32 h = hist[tid];
            lbase[tid] = h ? atomicAdd(&bcur[tid], h) : 0u;
            hist[tid] = 0;                   // reuse as local cursor
        }
        __syncthreads();
        #pragma unroll
        for (int k = 0; k < EB / 1024; ++k) {
            const int e = ebase + k * 1024 + tid;
            if (e < N_EDGES) {
                const int r = erow[e];
                const int c = ecol[e];
                const float w = ew[e];
                const int b = r >> 7;
                const u32 lr = atomicAdd(&hist[b], 1u);
                const u32 pos = lbase[b] + lr;
                if (pos < BCAP)              // deterministically never taken; guards memory
                    ebuf[(size_t)b * BCAP + pos] =
                        (u64)(u32)c | ((u64)(u32)(r & 127) << 16) | ((u64)bf16rne(w) << 32);
            }
        }
    } else if (blockIdx.x < SC_BLOCKS + SW_BLOCKS) {
        // ---- W1 fragment swizzle (K=256, N=128): 4096 ids ----
        const int id = (blockIdx.x - SC_BLOCKS) * 1024 + tid;   // 0..4095
        const int lane = id & 63;
        const int t    = (id >> 6) & 7;
        const int ks   = id >> 9;
        const int n     = t * 16 + (lane & 15);
        const int kbase = ks * 32 + (lane >> 4) * 8;
        u32 v[8];
        #pragma unroll
        for (int j = 0; j < 8; ++j) v[j] = bf16rne(W1[(kbase + j) * D1 + n]);
        uint4 w;
        w.x = v[0] | (v[1] << 16);
        w.y = v[2] | (v[3] << 16);
        w.z = v[4] | (v[5] << 16);
        w.w = v[6] | (v[7] << 16);
        ((uint4*)Bsw1)[id] = w;
    } else if (tid < 512) {
        // ---- W2 fragment swizzle (K=128, N=32): 512 ids ----
        const int id = tid;
        const int lane = id & 63;
        const int t    = (id >> 6) & 1;
        const int ks   = id >> 7;
        const int n     = t * 16 + (lane & 15);
        const int kbase = ks * 32 + (lane >> 4) * 8;
        u32 v[8];
        #pragma unroll
        for (int j = 0; j < 8; ++j) v[j] = bf16rne(W2[(kbase + j) * D2 + n]);
        uint4 w;
        w.x = v[0] | (v[1] << 16);
        w.y = v[2] | (v[3] << 16);
        w.z = v[4] | (v[5] << 16);
        w.w = v[6] | (v[7] << 16);
        ((uint4*)Bsw2)[id] = w;
    }
}

// ================= k2: fused  bucket-sort phase 2 | gemm1(MFMA) =================
// gemm1 writes s1b SLICE-MAJOR: plane t = features [t*16,t*16+16) for all rows.
__global__ __launch_bounds__(256) void gb_kernel(const float* __restrict__ x,
                                                 const u16* __restrict__ Bsw1,
                                                 u16* __restrict__ s1b,
                                                 const u32* __restrict__ bcur,
                                                 const u64* __restrict__ ebuf,
                                                 int* __restrict__ cnt,
                                                 u32* __restrict__ eg) {
    __shared__ u32 seg[128 * CAP];           // 24 KB (bucket branch only)
    __shared__ u32 lcnt[128];
    const int bid = blockIdx.x;
    if (bid < NB) {
        const int b = bid;
        for (int i = threadIdx.x; i < 128; i += 256) lcnt[i] = 0;
        __syncthreads();
        int n = (int)bcur[b];                // edges landed in this bucket (~2046)
        if (n > BCAP) n = BCAP;              // defensive clamp
        const u64* ep = ebuf + (size_t)b * BCAP;
        for (int i = threadIdx.x; i < n; i += 256) {
            const u64 e = ep[i];
            const u32 c  = (u32)(e & 0xFFFFu);
            const u32 lr = (u32)((e >> 16) & 0x7Fu);
            const u32 w  = (u32)(e >> 32);
            const u32 p = atomicAdd(&lcnt[lr], 1u);
            if (p < CAP)                     // max degree ~36; guards LDS
                seg[lr * CAP + p] = c | (w << 16);
        }
        __syncthreads();
        const int rows = min(128, N_NODES - b * 128);
        for (int i = threadIdx.x; i < rows; i += 256)
            cnt[b * 128 + i] = (int)min(lcnt[i], (u32)CAP);
        u32* dst = eg + (size_t)b * 128 * CAP;
        const int nvec = rows * (CAP / 4);   // uint4 count (rows*12)
        for (int i = threadIdx.x; i < nvec; i += 256)
            ((uint4*)dst)[i] = ((const uint4*)seg)[i];
    } else {
        // ---- gemm1: s1b(slice-major) = bf16(x[N,256]) @ W1 ----
        const int gb   = bid - NB;
        const int lane = threadIdx.x & 63;
        const int wave = threadIdx.x >> 6;
        const int rowbase = gb * 64 + wave * 16;
        const int m    = lane & 15;
        const int quad = lane >> 4;
        int arow = rowbase + m;
        if (arow >= N_NODES) arow = N_NODES - 1;
        const float* aptr = x + (size_t)arow * D0 + quad * 8;

        f32x4 acc[8];
        #pragma unroll
        for (int t = 0; t < 8; ++t) acc[t] = (f32x4){0.f, 0.f, 0.f, 0.f};

        #pragma unroll
        for (int ks = 0; ks < 8; ++ks) {
            const float4 f0 = *(const float4*)(aptr + ks * 32);
            const float4 f1 = *(const float4*)(aptr + ks * 32 + 4);
            bf16x8 a;
            a[0] = (short)bf16rne(f0.x); a[1] = (short)bf16rne(f0.y);
            a[2] = (short)bf16rne(f0.z); a[3] = (short)bf16rne(f0.w);
            a[4] = (short)bf16rne(f1.x); a[5] = (short)bf16rne(f1.y);
            a[6] = (short)bf16rne(f1.z); a[7] = (short)bf16rne(f1.w);
            const u16* bp = Bsw1 + ((size_t)(ks * 8) * 64 + lane) * 8;
            #pragma unroll
            for (int t = 0; t < 8; ++t) {
                const bf16x8 b = *(const bf16x8*)(bp + (size_t)t * 64 * 8);
                acc[t] = __builtin_amdgcn_mfma_f32_16x16x32_bf16(a, b, acc[t], 0, 0, 0);
            }
        }
        const int orow = rowbase + quad * 4;
        #pragma unroll
        for (int r = 0; r < 4; ++r) {
            const int row = orow + r;
            if (row < N_NODES) {
                #pragma unroll
                for (int t = 0; t < 8; ++t)
                    s1b[(size_t)t * PL + (size_t)row * 16 + m] = (u16)bf16rne(acc[t][r]);
            }
        }
    }
}

// ====== k3: XCD-sliced spmm1: hb[N,128](bf16) = relu(A @ s1b + b1) ==============
// slice = bid & 7 == XCD. Plane = 1.6MB contiguous, L2-resident (round 9 proved it:
// FETCH 248->66MB). eg loads are CACHED this round -- round 9's nt loads made every
// edge read pay full L3/HBM latency (dur 77->88 despite the FETCH collapse); a
// read-once stream self-evicts under LRU while the hot plane stays resident.
__global__ __launch_bounds__(256) void spmm1_slice_kernel(const int* __restrict__ cnt,
                                                          const u32* __restrict__ eg,
                                                          const u16* __restrict__ src,
                                                          const float* __restrict__ b1,
                                                          u16* __restrict__ hb) {
    const int tx = threadIdx.x;                        // 0..7 (feature pair)
    const int s  = blockIdx.x & 7;                     // slice == XCD
    const int rg = blockIdx.x >> 3;
    const int row = rg * 32 + threadIdx.y;
    if (row >= N_NODES) return;
    int len = cnt[row];
    if (len > CAP) len = CAP;
    const u32* ep = eg + (size_t)row * CAP;
    const u16* sp = src + (size_t)s * PL;              // slice plane base
    float ax0=0.f, ay0=0.f, ax1=0.f, ay1=0.f, ax2=0.f, ay2=0.f, ax3=0.f, ay3=0.f;
    int j = 0;
    for (; j + 7 < len; j += 8) {                      // 8 gathers in flight
        const uint4 e4a = *(const uint4*)(ep + j);     // cached broadcast
        const uint4 e4b = *(const uint4*)(ep + j + 4);
        const u32 v0 = ((const u32*)(sp + (size_t)(e4a.x & 0xFFFFu) * 16))[tx];
        const u32 v1 = ((const u32*)(sp + (size_t)(e4a.y & 0xFFFFu) * 16))[tx];
        const u32 v2 = ((const u32*)(sp + (size_t)(e4a.z & 0xFFFFu) * 16))[tx];
        const u32 v3 = ((const u32*)(sp + (size_t)(e4a.w & 0xFFFFu) * 16))[tx];
        const u32 v4 = ((const u32*)(sp + (size_t)(e4b.x & 0xFFFFu) * 16))[tx];
        const u32 v5 = ((const u32*)(sp + (size_t)(e4b.y & 0xFFFFu) * 16))[tx];
        const u32 v6 = ((const u32*)(sp + (size_t)(e4b.z & 0xFFFFu) * 16))[tx];
        const u32 v7 = ((const u32*)(sp + (size_t)(e4b.w & 0xFFFFu) * 16))[tx];
        const float w0 = bfhi(e4a.x), w1 = bfhi(e4a.y), w2 = bfhi(e4a.z), w3 = bfhi(e4a.w);
        const float w4 = bfhi(e4b.x), w5 = bfhi(e4b.y), w6 = bfhi(e4b.z), w7 = bfhi(e4b.w);
        ax0 += w0 * bflo(v0); ay0 += w0 * bfhi(v0);
        ax1 += w1 * bflo(v1); ay1 += w1 * bfhi(v1);
        ax2 += w2 * bflo(v2); ay2 += w2 * bfhi(v2);
        ax3 += w3 * bflo(v3); ay3 += w3 * bfhi(v3);
        ax0 += w4 * bflo(v4); ay0 += w4 * bfhi(v4);
        ax1 += w5 * bflo(v5); ay1 += w5 * bfhi(v5);
        ax2 += w6 * bflo(v6); ay2 += w6 * bfhi(v6);
        ax3 += w7 * bflo(v7); ay3 += w7 * bfhi(v7);
    }
    for (; j + 3 < len; j += 4) {
        const uint4 e4 = *(const uint4*)(ep + j);
        const u32 v0 = ((const u32*)(sp + (size_t)(e4.x & 0xFFFFu) * 16))[tx];
        const u32 v1 = ((const u32*)(sp + (size_t)(e4.y & 0xFFFFu) * 16))[tx];
        const u32 v2 = ((const u32*)(sp + (size_t)(e4.z & 0xFFFFu) * 16))[tx];
        const u32 v3 = ((const u32*)(sp + (size_t)(e4.w & 0xFFFFu) * 16))[tx];
        const float w0 = bfhi(e4.x), w1 = bfhi(e4.y), w2 = bfhi(e4.z), w3 = bfhi(e4.w);
        ax0 += w0 * bflo(v0); ay0 += w0 * bfhi(v0);
        ax1 += w1 * bflo(v1); ay1 += w1 * bfhi(v1);
        ax2 += w2 * bflo(v2); ay2 += w2 * bfhi(v2);
        ax3 += w3 * bflo(v3); ay3 += w3 * bfhi(v3);
    }
    for (; j < len; ++j) {
        const u32 e0 = ep[j];
        const u32 v0 = ((const u32*)(sp + (size_t)(e0 & 0xFFFFu) * 16))[tx];
        const float w0 = bfhi(e0);
        ax0 += w0 * bflo(v0); ay0 += w0 * bfhi(v0);
    }
    const float2 bv = ((const float2*)(b1 + s * 16))[tx];
    float vx = ax0 + ax1 + ax2 + ax3 + bv.x; vx = vx > 0.f ? vx : 0.f;
    float vy = ay0 + ay1 + ay2 + ay3 + bv.y; vy = vy > 0.f ? vy : 0.f;
    __builtin_nontemporal_store(bf16rne(vx) | (bf16rne(vy) << 16),
                                (u32*)(hb + (size_t)row * D1 + s * 16) + tx);
}

// ================= gemm2 MFMA: s2b[N,32](bf16) = hb[N,128] @ W2 =================
__global__ __launch_bounds__(256) void gemm2_mfma_kernel(const u16* __restrict__ hb,
                                                         const u16* __restrict__ Bsw2,
                                                         u16* __restrict__ s2b) {
    const int lane = threadIdx.x & 63;
    const int wave = threadIdx.x >> 6;
    const int rowbase = blockIdx.x * 64 + wave * 16;
    const int m    = lane & 15;
    const int quad = lane >> 4;
    int arow = rowbase + m;
    if (arow >= N_NODES) arow = N_NODES - 1;
    const u16* aptr = hb + (size_t)arow * D1 + quad * 8;

    f32x4 acc0 = (f32x4){0.f,0.f,0.f,0.f};
    f32x4 acc1 = (f32x4){0.f,0.f,0.f,0.f};

    #pragma unroll
    for (int ks = 0; ks < 4; ++ks) {
        const bf16x8 a = *(const bf16x8*)(aptr + ks * 32);
        const u16* bp = Bsw2 + ((size_t)(ks * 2) * 64 + lane) * 8;
        const bf16x8 b0 = *(const bf16x8*)(bp);
        const bf16x8 b1 = *(const bf16x8*)(bp + (size_t)64 * 8);
        acc0 = __builtin_amdgcn_mfma_f32_16x16x32_bf16(a, b0, acc0, 0, 0, 0);
        acc1 = __builtin_amdgcn_mfma_f32_16x16x32_bf16(a, b1, acc1, 0, 0, 0);
    }
    const int orow = rowbase + quad * 4;
    #pragma unroll
    for (int r = 0; r < 4; ++r) {
        const int row = orow + r;
        if (row < N_NODES) {
            u16* op = s2b + (size_t)row * D2 + m;
            op[0]  = (u16)bf16rne(acc0[r]);
            op[16] = (u16)bf16rne(acc1[r]);
        }
    }
}

// ================= spmm2: out[N,32](f32) = relu(A @ s2b + b2) ===================
// s2b table = 3.2MB < 4MB per-XCD L2: gathers warm into L2; eg cached (round-9
// lesson: nt loads turn a cheap stream into per-load L3 latency).
__global__ __launch_bounds__(256) void spmm_csr32_kernel(const int* __restrict__ cnt,
                                                         const u32* __restrict__ eg,
                                                         const u16* __restrict__ src,
                                                         const float* __restrict__ bias,
                                                         float* __restrict__ out) {
    const int lane = threadIdx.x;                      // 0..15
    const int row  = blockIdx.x * 16 + threadIdx.y;
    if (row >= N_NODES) return;
    int len = cnt[row];
    if (len > CAP) len = CAP;
    const u32* ep = eg + (size_t)row * CAP;
    float ax0=0.f, ay0=0.f, ax1=0.f, ay1=0.f, ax2=0.f, ay2=0.f, ax3=0.f, ay3=0.f;
    int j = 0;
    for (; j + 7 < len; j += 8) {                      // 8 loads in flight
        const uint4 e4a = *(const uint4*)(ep + j);
        const uint4 e4b = *(const uint4*)(ep + j + 4);
        const u32 v0 = ((const u32*)(src + (size_t)(e4a.x & 0xFFFFu) * D2))[lane];
        const u32 v1 = ((const u32*)(src + (size_t)(e4a.y & 0xFFFFu) * D2))[lane];
        const u32 v2 = ((const u32*)(src + (size_t)(e4a.z & 0xFFFFu) * D2))[lane];
        const u32 v3 = ((const u32*)(src + (size_t)(e4a.w & 0xFFFFu) * D2))[lane];
        const u32 v4 = ((const u32*)(src + (size_t)(e4b.x & 0xFFFFu) * D2))[lane];
        const u32 v5 = ((const u32*)(src + (size_t)(e4b.y & 0xFFFFu) * D2))[lane];
        const u32 v6 = ((const u32*)(src + (size_t)(e4b.z & 0xFFFFu) * D2))[lane];
        const u32 v7 = ((const u32*)(src + (size_t)(e4b.w & 0xFFFFu) * D2))[lane];
        const float w0 = bfhi(e4a.x), w1 = bfhi(e4a.y), w2 = bfhi(e4a.z), w3 = bfhi(e4a.w);
        const float w4 = bfhi(e4b.x), w5 = bfhi(e4b.y), w6 = bfhi(e4b.z), w7 = bfhi(e4b.w);
        ax0 += w0 * bflo(v0); ay0 += w0 * bfhi(v0);
        ax1 += w1 * bflo(v1); ay1 += w1 * bfhi(v1);
        ax2 += w2 * bflo(v2); ay2 += w2 * bfhi(v2);
        ax3 += w3 * bflo(v3); ay3 += w3 * bfhi(v3);
        ax0 += w4 * bflo(v4); ay0 += w4 * bfhi(v4);
        ax1 += w5 * bflo(v5); ay1 += w5 * bfhi(v5);
        ax2 += w6 * bflo(v6); ay2 += w6 * bfhi(v6);
        ax3 += w7 * bflo(v7); ay3 += w7 * bfhi(v7);
    }
    for (; j + 3 < len; j += 4) {
        const uint4 e4 = *(const uint4*)(ep + j);
        const u32 v0 = ((const u32*)(src + (size_t)(e4.x & 0xFFFFu) * D2))[lane];
        const u32 v1 = ((const u32*)(src + (size_t)(e4.y & 0xFFFFu) * D2))[lane];
        const u32 v2 = ((const u32*)(src + (size_t)(e4.z & 0xFFFFu) * D2))[lane];
        const u32 v3 = ((const u32*)(src + (size_t)(e4.w & 0xFFFFu) * D2))[lane];
        const float w0 = bfhi(e4.x), w1 = bfhi(e4.y), w2 = bfhi(e4.z), w3 = bfhi(e4.w);
        ax0 += w0 * bflo(v0); ay0 += w0 * bfhi(v0);
        ax1 += w1 * bflo(v1); ay1 += w1 * bfhi(v1);
        ax2 += w2 * bflo(v2); ay2 += w2 * bfhi(v2);
        ax3 += w3 * bflo(v3); ay3 += w3 * bfhi(v3);
    }
    for (; j < len; ++j) {
        const u32 e0 = ep[j];
        const u32 v0 = ((const u32*)(src + (size_t)(e0 & 0xFFFFu) * D2))[lane];
        const float w0 = bfhi(e0);
        ax0 += w0 * bflo(v0); ay0 += w0 * bfhi(v0);
    }
    const float2 b2v = ((const float2*)bias)[lane];
    float vx = ax0 + ax1 + ax2 + ax3 + b2v.x; vx = vx > 0.f ? vx : 0.f;
    float vy = ay0 + ay1 + ay2 + ay3 + b2v.y; vy = vy > 0.f ? vy : 0.f;
    union { float2 f; u64 u; } o; o.f = make_float2(vx, vy);
    __builtin_nontemporal_store(o.u, (u64*)(out + (size_t)row * D2) + lane);
}

extern "C" void kernel_launch(void* const* d_in, const int* in_sizes, int n_in,
                              void* d_out, int out_size, void* d_ws, size_t ws_size,
                              hipStream_t stream) {
    const float* x    = (const float*)d_in[0];
    const int*   erow = (const int*)  d_in[1];
    const int*   ecol = (const int*)  d_in[2];
    const float* ew   = (const float*)d_in[3];
    const float* W1   = (const float*)d_in[4];
    const float* b1   = (const float*)d_in[5];
    const float* W2   = (const float*)d_in[6];
    const float* b2   = (const float*)d_in[7];
    float* out = (float*)d_out;

    // workspace layout (~49 MB, no aliasing):
    //   cnt[N int]  bcur[512 u32]  eg[N*CAP u32]  Bsw1[32768 u16]  Bsw2[4096 u16]
    //   s1b[8 planes x N*16 u16]  hb[N*128 u16]  s2b[N*32 u16]  ebuf[NB*BCAP u64]
    int* cnt   = (int*)d_ws;
    u32* bcur  = (u32*)(cnt + N_NODES);
    u32* eg    = (u32*)(bcur + 512);
    u16* Bsw1  = (u16*)(eg + (size_t)N_NODES * CAP);
    u16* Bsw2  = Bsw1 + 8 * 8 * 64 * 8;
    u16* s1b   = Bsw2 + 4 * 2 * 64 * 8;
    u16* hb    = s1b + 8 * PL;
    u16* s2b   = hb + (size_t)N_NODES * D1;
    u64* ebuf  = (u64*)(s2b + (size_t)N_NODES * D2);

    hipMemsetAsync(bcur, 0, 512 * sizeof(u32), stream);
    // k1: bucket-sort phase 1 (scatter) | W1 swizzle | W2 swizzle
    scatter_kernel<<<SC_BLOCKS + SW_BLOCKS + 1, 1024, 0, stream>>>(
        erow, ecol, ew, bcur, ebuf, W1, Bsw1, W2, Bsw2);
    // k2: bucket-sort phase 2 | gemm1 (slice-major s1b)
    gb_kernel<<<NB + G1_BLOCKS, 256, 0, stream>>>(x, Bsw1, s1b, bcur, ebuf, cnt, eg);
    // k3: XCD-sliced layer-1 aggregate (slice = bid&7 == XCD; 1.6MB L2-resident plane)
    spmm1_slice_kernel<<<RG_BLOCKS * 8, dim3(8, 32), 0, stream>>>(cnt, eg, s1b, b1, hb);
    // k4: layer-2 dense projection (MFMA)
    gemm2_mfma_kernel<<<(N_NODES + 63) / 64, 256, 0, stream>>>(hb, Bsw2, s2b);
    // k5: layer-2 aggregate
    spmm_csr32_kernel<<<(N_NODES + 15) / 16, dim3(16, 16), 0, stream>>>(cnt, eg, s2b, b2, out);
}

// Round 11
// 183.215 us; speedup vs baseline: 1.3152x; 1.0782x over previous
//
#include <hip/hip_runtime.h>

#define N_NODES 50000
#define N_EDGES 800000
#define D0 256
#define D1 128
#define D2 32
#define CAP 48             // bucket capacity per row (max degree ~36; P(>48) ~ 8-sigma)
#define NB 391             // row-buckets of 128 rows: ceil(50000/128)
#define BCAP 3072          // u64 slots per bucket region (expected ~2046/bucket; +22 sigma)
#define EB 8192            // edges per scatter block (8/thread @ 1024 threads)
#define SC_BLOCKS 98       // ceil(800000/8192)
#define SW_BLOCKS 4        // W1 swizzle: 4096 threads = 4 x 1024
#define G1_BLOCKS 782      // ceil(50000/64)
#define RG_BLOCKS 1563     // ceil(50000/32) row-groups for the sliced spmm1
#define NSL 4              // slices (round 10: 8 slices = 8x redundant edge decode)
#define PL ((size_t)N_NODES * 32)   // u16 elements per s1b slice plane (3.2 MB < 4MB L2)

typedef unsigned short u16;
typedef unsigned int   u32;
typedef unsigned long long u64;
typedef __attribute__((ext_vector_type(8))) short bf16x8;
typedef __attribute__((ext_vector_type(4))) float f32x4;

__device__ inline u32 bf16rne(float f) {
    union { float f; u32 u; } c; c.f = f;
    return (c.u + 0x7FFFu + ((c.u >> 16) & 1u)) >> 16;
}
__device__ inline float bfhi(u32 v) {      // high 16 bits hold the bf16
    union { u32 u; float f; } c; c.u = v & 0xFFFF0000u; return c.f;
}
__device__ inline float bflo(u32 v) {      // low 16 bits hold the bf16
    union { u32 u; float f; } c; c.u = v << 16; return c.f;
}

// ==== k1: bucket-sort phase 1 (scatter) | W1 swizzle | W2 swizzle ===============
__global__ __launch_bounds__(1024) void scatter_kernel(const int* __restrict__ erow,
                                                       const int* __restrict__ ecol,
                                                       const float* __restrict__ ew,
                                                       u32* __restrict__ bcur,
                                                       u64* __restrict__ ebuf,
                                                       const float* __restrict__ W1,
                                                       u16* __restrict__ Bsw1,
                                                       const float* __restrict__ W2,
                                                       u16* __restrict__ Bsw2) {
    __shared__ u32 hist[NB];
    __shared__ u32 lbase[NB];
    const int tid = threadIdx.x;
    if (blockIdx.x < SC_BLOCKS) {
        if (tid < NB) hist[tid] = 0;
        __syncthreads();
        const int ebase = blockIdx.x * EB;
        #pragma unroll
        for (int k = 0; k < EB / 1024; ++k) {
            const int e = ebase + k * 1024 + tid;
            if (e < N_EDGES) atomicAdd(&hist[erow[e] >> 7], 1u);
        }
        __syncthreads();
        if (tid < NB) {
            const u32 h = hist[tid];
            lbase[tid] = h ? atomicAdd(&bcur[tid], h) : 0u;
            hist[tid] = 0;                   // reuse as local cursor
        }
        __syncthreads();
        #pragma unroll
        for (int k = 0; k < EB / 1024; ++k) {
            const int e = ebase + k * 1024 + tid;
            if (e < N_EDGES) {
                const int r = erow[e];
                const int c = ecol[e];
                const float w = ew[e];
                const int b = r >> 7;
                const u32 lr = atomicAdd(&hist[b], 1u);
                const u32 pos = lbase[b] + lr;
                if (pos < BCAP)              // deterministically never taken; guards memory
                    ebuf[(size_t)b * BCAP + pos] =
                        (u64)(u32)c | ((u64)(u32)(r & 127) << 16) | ((u64)bf16rne(w) << 32);
            }
        }
    } else if (blockIdx.x < SC_BLOCKS + SW_BLOCKS) {
        // ---- W1 fragment swizzle (K=256, N=128): 4096 ids ----
        const int id = (blockIdx.x - SC_BLOCKS) * 1024 + tid;   // 0..4095
        const int lane = id & 63;
        const int t    = (id >> 6) & 7;
        const int ks   = id >> 9;
        const int n     = t * 16 + (lane & 15);
        const int kbase = ks * 32 + (lane >> 4) * 8;
        u32 v[8];
        #pragma unroll
        for (int j = 0; j < 8; ++j) v[j] = bf16rne(W1[(kbase + j) * D1 + n]);
        uint4 w;
        w.x = v[0] | (v[1] << 16);
        w.y = v[2] | (v[3] << 16);
        w.z = v[4] | (v[5] << 16);
        w.w = v[6] | (v[7] << 16);
        ((uint4*)Bsw1)[id] = w;
    } else if (tid < 512) {
        // ---- W2 fragment swizzle (K=128, N=32): 512 ids ----
        const int id = tid;
        const int lane = id & 63;
        const int t    = (id >> 6) & 1;
        const int ks   = id >> 7;
        const int n     = t * 16 + (lane & 15);
        const int kbase = ks * 32 + (lane >> 4) * 8;
        u32 v[8];
        #pragma unroll
        for (int j = 0; j < 8; ++j) v[j] = bf16rne(W2[(kbase + j) * D2 + n]);
        uint4 w;
        w.x = v[0] | (v[1] << 16);
        w.y = v[2] | (v[3] << 16);
        w.z = v[4] | (v[5] << 16);
        w.w = v[6] | (v[7] << 16);
        ((uint4*)Bsw2)[id] = w;
    }
}

// ================= k2: fused  bucket-sort phase 2 | gemm1(MFMA) =================
// gemm1 writes s1b SLICE-MAJOR (4 planes of [N][32]): feature f = t*16+m lives in
// plane t>>1 at offset row*32 + (t&1)*16 + m.
__global__ __launch_bounds__(256) void gb_kernel(const float* __restrict__ x,
                                                 const u16* __restrict__ Bsw1,
                                                 u16* __restrict__ s1b,
                                                 const u32* __restrict__ bcur,
                                                 const u64* __restrict__ ebuf,
                                                 int* __restrict__ cnt,
                                                 u32* __restrict__ eg) {
    __shared__ u32 seg[128 * CAP];           // 24 KB (bucket branch only)
    __shared__ u32 lcnt[128];
    const int bid = blockIdx.x;
    if (bid < NB) {
        const int b = bid;
        for (int i = threadIdx.x; i < 128; i += 256) lcnt[i] = 0;
        __syncthreads();
        int n = (int)bcur[b];                // edges landed in this bucket (~2046)
        if (n > BCAP) n = BCAP;              // defensive clamp
        const u64* ep = ebuf + (size_t)b * BCAP;
        for (int i = threadIdx.x; i < n; i += 256) {
            const u64 e = ep[i];
            const u32 c  = (u32)(e & 0xFFFFu);
            const u32 lr = (u32)((e >> 16) & 0x7Fu);
            const u32 w  = (u32)(e >> 32);
            const u32 p = atomicAdd(&lcnt[lr], 1u);
            if (p < CAP)                     // max degree ~36; guards LDS
                seg[lr * CAP + p] = c | (w << 16);
        }
        __syncthreads();
        const int rows = min(128, N_NODES - b * 128);
        for (int i = threadIdx.x; i < rows; i += 256)
            cnt[b * 128 + i] = (int)min(lcnt[i], (u32)CAP);
        u32* dst = eg + (size_t)b * 128 * CAP;
        const int nvec = rows * (CAP / 4);   // uint4 count (rows*12)
        for (int i = threadIdx.x; i < nvec; i += 256)
            ((uint4*)dst)[i] = ((const uint4*)seg)[i];
    } else {
        // ---- gemm1: s1b(4-plane slice-major) = bf16(x[N,256]) @ W1 ----
        const int gb   = bid - NB;
        const int lane = threadIdx.x & 63;
        const int wave = threadIdx.x >> 6;
        const int rowbase = gb * 64 + wave * 16;
        const int m    = lane & 15;
        const int quad = lane >> 4;
        int arow = rowbase + m;
        if (arow >= N_NODES) arow = N_NODES - 1;
        const float* aptr = x + (size_t)arow * D0 + quad * 8;

        f32x4 acc[8];
        #pragma unroll
        for (int t = 0; t < 8; ++t) acc[t] = (f32x4){0.f, 0.f, 0.f, 0.f};

        #pragma unroll
        for (int ks = 0; ks < 8; ++ks) {
            const float4 f0 = *(const float4*)(aptr + ks * 32);
            const float4 f1 = *(const float4*)(aptr + ks * 32 + 4);
            bf16x8 a;
            a[0] = (short)bf16rne(f0.x); a[1] = (short)bf16rne(f0.y);
            a[2] = (short)bf16rne(f0.z); a[3] = (short)bf16rne(f0.w);
            a[4] = (short)bf16rne(f1.x); a[5] = (short)bf16rne(f1.y);
            a[6] = (short)bf16rne(f1.z); a[7] = (short)bf16rne(f1.w);
            const u16* bp = Bsw1 + ((size_t)(ks * 8) * 64 + lane) * 8;
            #pragma unroll
            for (int t = 0; t < 8; ++t) {
                const bf16x8 b = *(const bf16x8*)(bp + (size_t)t * 64 * 8);
                acc[t] = __builtin_amdgcn_mfma_f32_16x16x32_bf16(a, b, acc[t], 0, 0, 0);
            }
        }
        const int orow = rowbase + quad * 4;
        #pragma unroll
        for (int r = 0; r < 4; ++r) {
            const int row = orow + r;
            if (row < N_NODES) {
                #pragma unroll
                for (int t = 0; t < 8; ++t)
                    s1b[(size_t)(t >> 1) * PL + (size_t)row * 32 + (t & 1) * 16 + m] =
                        (u16)bf16rne(acc[t][r]);
            }
        }
    }
}

// ====== k3: XCD-sliced spmm1: hb[N,128](bf16) = relu(A @ s1b + b1) ==============
// 4 slices x 32 features (3.2MB plane, L2-resident; XCDs {k,k+4} each hold a copy
// of slice k). Halves round-10's 8x redundant edge decode: eg stream 77->38MB,
// gather count 51M->26M (8B each). block (8,32): tx gathers uint2 = 4 features.
__global__ __launch_bounds__(256) void spmm1_slice_kernel(const int* __restrict__ cnt,
                                                          const u32* __restrict__ eg,
                                                          const u16* __restrict__ src,
                                                          const float* __restrict__ b1,
                                                          u16* __restrict__ hb) {
    const int tx = threadIdx.x;                        // 0..7 (4 features each)
    const int s  = blockIdx.x & (NSL - 1);             // slice; XCD k holds slice k&3
    const int rg = blockIdx.x >> 2;
    const int row = rg * 32 + threadIdx.y;
    if (row >= N_NODES) return;
    int len = cnt[row];
    if (len > CAP) len = CAP;
    const u32* ep = eg + (size_t)row * CAP;
    const u16* sp = src + (size_t)s * PL;              // slice plane base
    float4 a0 = {0.f,0.f,0.f,0.f}, a1 = {0.f,0.f,0.f,0.f};
    float4 a2 = {0.f,0.f,0.f,0.f}, a3 = {0.f,0.f,0.f,0.f};
    int j = 0;
    for (; j + 7 < len; j += 8) {                      // 8 gathers in flight
        const uint4 e4a = *(const uint4*)(ep + j);     // cached broadcast
        const uint4 e4b = *(const uint4*)(ep + j + 4);
        const uint2 v0 = ((const uint2*)(sp + (size_t)(e4a.x & 0xFFFFu) * 32))[tx];
        const uint2 v1 = ((const uint2*)(sp + (size_t)(e4a.y & 0xFFFFu) * 32))[tx];
        const uint2 v2 = ((const uint2*)(sp + (size_t)(e4a.z & 0xFFFFu) * 32))[tx];
        const uint2 v3 = ((const uint2*)(sp + (size_t)(e4a.w & 0xFFFFu) * 32))[tx];
        const uint2 v4 = ((const uint2*)(sp + (size_t)(e4b.x & 0xFFFFu) * 32))[tx];
        const uint2 v5 = ((const uint2*)(sp + (size_t)(e4b.y & 0xFFFFu) * 32))[tx];
        const uint2 v6 = ((const uint2*)(sp + (size_t)(e4b.z & 0xFFFFu) * 32))[tx];
        const uint2 v7 = ((const uint2*)(sp + (size_t)(e4b.w & 0xFFFFu) * 32))[tx];
        const float w0 = bfhi(e4a.x), w1 = bfhi(e4a.y), w2 = bfhi(e4a.z), w3 = bfhi(e4a.w);
        const float w4 = bfhi(e4b.x), w5 = bfhi(e4b.y), w6 = bfhi(e4b.z), w7 = bfhi(e4b.w);
        a0.x += w0 * bflo(v0.x); a0.y += w0 * bfhi(v0.x);
        a0.z += w0 * bflo(v0.y); a0.w += w0 * bfhi(v0.y);
        a1.x += w1 * bflo(v1.x); a1.y += w1 * bfhi(v1.x);
        a1.z += w1 * bflo(v1.y); a1.w += w1 * bfhi(v1.y);
        a2.x += w2 * bflo(v2.x); a2.y += w2 * bfhi(v2.x);
        a2.z += w2 * bflo(v2.y); a2.w += w2 * bfhi(v2.y);
        a3.x += w3 * bflo(v3.x); a3.y += w3 * bfhi(v3.x);
        a3.z += w3 * bflo(v3.y); a3.w += w3 * bfhi(v3.y);
        a0.x += w4 * bflo(v4.x); a0.y += w4 * bfhi(v4.x);
        a0.z += w4 * bflo(v4.y); a0.w += w4 * bfhi(v4.y);
        a1.x += w5 * bflo(v5.x); a1.y += w5 * bfhi(v5.x);
        a1.z += w5 * bflo(v5.y); a1.w += w5 * bfhi(v5.y);
        a2.x += w6 * bflo(v6.x); a2.y += w6 * bfhi(v6.x);
        a2.z += w6 * bflo(v6.y); a2.w += w6 * bfhi(v6.y);
        a3.x += w7 * bflo(v7.x); a3.y += w7 * bfhi(v7.x);
        a3.z += w7 * bflo(v7.y); a3.w += w7 * bfhi(v7.y);
    }
    for (; j + 3 < len; j += 4) {
        const uint4 e4 = *(const uint4*)(ep + j);
        const uint2 v0 = ((const uint2*)(sp + (size_t)(e4.x & 0xFFFFu) * 32))[tx];
        const uint2 v1 = ((const uint2*)(sp + (size_t)(e4.y & 0xFFFFu) * 32))[tx];
        const uint2 v2 = ((const uint2*)(sp + (size_t)(e4.z & 0xFFFFu) * 32))[tx];
        const uint2 v3 = ((const uint2*)(sp + (size_t)(e4.w & 0xFFFFu) * 32))[tx];
        const float w0 = bfhi(e4.x), w1 = bfhi(e4.y), w2 = bfhi(e4.z), w3 = bfhi(e4.w);
        a0.x += w0 * bflo(v0.x); a0.y += w0 * bfhi(v0.x);
        a0.z += w0 * bflo(v0.y); a0.w += w0 * bfhi(v0.y);
        a1.x += w1 * bflo(v1.x); a1.y += w1 * bfhi(v1.x);
        a1.z += w1 * bflo(v1.y); a1.w += w1 * bfhi(v1.y);
        a2.x += w2 * bflo(v2.x); a2.y += w2 * bfhi(v2.x);
        a2.z += w2 * bflo(v2.y); a2.w += w2 * bfhi(v2.y);
        a3.x += w3 * bflo(v3.x); a3.y += w3 * bfhi(v3.x);
        a3.z += w3 * bflo(v3.y); a3.w += w3 * bfhi(v3.y);
    }
    for (; j < len; ++j) {
        const u32 e0 = ep[j];
        const float w0 = bfhi(e0);
        const uint2 v0 = ((const uint2*)(sp + (size_t)(e0 & 0xFFFFu) * 32))[tx];
        a0.x += w0 * bflo(v0.x); a0.y += w0 * bfhi(v0.x);
        a0.z += w0 * bflo(v0.y); a0.w += w0 * bfhi(v0.y);
    }
    const float4 bv = ((const float4*)(b1 + s * 32))[tx];
    float vx = a0.x + a1.x + a2.x + a3.x + bv.x; vx = vx > 0.f ? vx : 0.f;
    float vy = a0.y + a1.y + a2.y + a3.y + bv.y; vy = vy > 0.f ? vy : 0.f;
    float vz = a0.z + a1.z + a2.z + a3.z + bv.z; vz = vz > 0.f ? vz : 0.f;
    float vw = a0.w + a1.w + a2.w + a3.w + bv.w; vw = vw > 0.f ? vw : 0.f;
    const u64 o = (u64)(bf16rne(vx) | (bf16rne(vy) << 16)) |
                  ((u64)(bf16rne(vz) | (bf16rne(vw) << 16)) << 32);
    __builtin_nontemporal_store(o, (u64*)(hb + (size_t)row * D1 + s * 32) + tx);
}

// ================= gemm2 MFMA: s2b[N,32](bf16) = hb[N,128] @ W2 =================
__global__ __launch_bounds__(256) void gemm2_mfma_kernel(const u16* __restrict__ hb,
                                                         const u16* __restrict__ Bsw2,
                                                         u16* __restrict__ s2b) {
    const int lane = threadIdx.x & 63;
    const int wave = threadIdx.x >> 6;
    const int rowbase = blockIdx.x * 64 + wave * 16;
    const int m    = lane & 15;
    const int quad = lane >> 4;
    int arow = rowbase + m;
    if (arow >= N_NODES) arow = N_NODES - 1;
    const u16* aptr = hb + (size_t)arow * D1 + quad * 8;

    f32x4 acc0 = (f32x4){0.f,0.f,0.f,0.f};
    f32x4 acc1 = (f32x4){0.f,0.f,0.f,0.f};

    #pragma unroll
    for (int ks = 0; ks < 4; ++ks) {
        const bf16x8 a = *(const bf16x8*)(aptr + ks * 32);
        const u16* bp = Bsw2 + ((size_t)(ks * 2) * 64 + lane) * 8;
        const bf16x8 b0 = *(const bf16x8*)(bp);
        const bf16x8 b1 = *(const bf16x8*)(bp + (size_t)64 * 8);
        acc0 = __builtin_amdgcn_mfma_f32_16x16x32_bf16(a, b0, acc0, 0, 0, 0);
        acc1 = __builtin_amdgcn_mfma_f32_16x16x32_bf16(a, b1, acc1, 0, 0, 0);
    }
    const int orow = rowbase + quad * 4;
    #pragma unroll
    for (int r = 0; r < 4; ++r) {
        const int row = orow + r;
        if (row < N_NODES) {
            u16* op = s2b + (size_t)row * D2 + m;
            op[0]  = (u16)bf16rne(acc0[r]);
            op[16] = (u16)bf16rne(acc1[r]);
        }
    }
}

// ================= spmm2: out[N,32](f32) = relu(A @ s2b + b2) ===================
// s2b table = 3.2MB < 4MB per-XCD L2: gathers warm into L2; eg cached.
__global__ __launch_bounds__(256) void spmm_csr32_kernel(const int* __restrict__ cnt,
                                                         const u32* __restrict__ eg,
                                                         const u16* __restrict__ src,
                                                         const float* __restrict__ bias,
                                                         float* __restrict__ out) {
    const int lane = threadIdx.x;                      // 0..15
    const int row  = blockIdx.x * 16 + threadIdx.y;
    if (row >= N_NODES) return;
    int len = cnt[row];
    if (len > CAP) len = CAP;
    const u32* ep = eg + (size_t)row * CAP;
    float ax0=0.f, ay0=0.f, ax1=0.f, ay1=0.f, ax2=0.f, ay2=0.f, ax3=0.f, ay3=0.f;
    int j = 0;
    for (; j + 7 < len; j += 8) {                      // 8 loads in flight
        const uint4 e4a = *(const uint4*)(ep + j);
        const uint4 e4b = *(const uint4*)(ep + j + 4);
        const u32 v0 = ((const u32*)(src + (size_t)(e4a.x & 0xFFFFu) * D2))[lane];
        const u32 v1 = ((const u32*)(src + (size_t)(e4a.y & 0xFFFFu) * D2))[lane];
        const u32 v2 = ((const u32*)(src + (size_t)(e4a.z & 0xFFFFu) * D2))[lane];
        const u32 v3 = ((const u32*)(src + (size_t)(e4a.w & 0xFFFFu) * D2))[lane];
        const u32 v4 = ((const u32*)(src + (size_t)(e4b.x & 0xFFFFu) * D2))[lane];
        const u32 v5 = ((const u32*)(src + (size_t)(e4b.y & 0xFFFFu) * D2))[lane];
        const u32 v6 = ((const u32*)(src + (size_t)(e4b.z & 0xFFFFu) * D2))[lane];
        const u32 v7 = ((const u32*)(src + (size_t)(e4b.w & 0xFFFFu) * D2))[lane];
        const float w0 = bfhi(e4a.x), w1 = bfhi(e4a.y), w2 = bfhi(e4a.z), w3 = bfhi(e4a.w);
        const float w4 = bfhi(e4b.x), w5 = bfhi(e4b.y), w6 = bfhi(e4b.z), w7 = bfhi(e4b.w);
        ax0 += w0 * bflo(v0); ay0 += w0 * bfhi(v0);
        ax1 += w1 * bflo(v1); ay1 += w1 * bfhi(v1);
        ax2 += w2 * bflo(v2); ay2 += w2 * bfhi(v2);
        ax3 += w3 * bflo(v3); ay3 += w3 * bfhi(v3);
        ax0 += w4 * bflo(v4); ay0 += w4 * bfhi(v4);
        ax1 += w5 * bflo(v5); ay1 += w5 * bfhi(v5);
        ax2 += w6 * bflo(v6); ay2 += w6 * bfhi(v6);
        ax3 += w7 * bflo(v7); ay3 += w7 * bfhi(v7);
    }
    for (; j + 3 < len; j += 4) {
        const uint4 e4 = *(const uint4*)(ep + j);
        const u32 v0 = ((const u32*)(src + (size_t)(e4.x & 0xFFFFu) * D2))[lane];
        const u32 v1 = ((const u32*)(src + (size_t)(e4.y & 0xFFFFu) * D2))[lane];
        const u32 v2 = ((const u32*)(src + (size_t)(e4.z & 0xFFFFu) * D2))[lane];
        const u32 v3 = ((const u32*)(src + (size_t)(e4.w & 0xFFFFu) * D2))[lane];
        const float w0 = bfhi(e4.x), w1 = bfhi(e4.y), w2 = bfhi(e4.z), w3 = bfhi(e4.w);
        ax0 += w0 * bflo(v0); ay0 += w0 * bfhi(v0);
        ax1 += w1 * bflo(v1); ay1 += w1 * bfhi(v1);
        ax2 += w2 * bflo(v2); ay2 += w2 * bfhi(v2);
        ax3 += w3 * bflo(v3); ay3 += w3 * bfhi(v3);
    }
    for (; j < len; ++j) {
        const u32 e0 = ep[j];
        const u32 v0 = ((const u32*)(src + (size_t)(e0 & 0xFFFFu) * D2))[lane];
        const float w0 = bfhi(e0);
        ax0 += w0 * bflo(v0); ay0 += w0 * bfhi(v0);
    }
    const float2 b2v = ((const float2*)bias)[lane];
    float vx = ax0 + ax1 + ax2 + ax3 + b2v.x; vx = vx > 0.f ? vx : 0.f;
    float vy = ay0 + ay1 + ay2 + ay3 + b2v.y; vy = vy > 0.f ? vy : 0.f;
    union { float2 f; u64 u; } o; o.f = make_float2(vx, vy);
    __builtin_nontemporal_store(o.u, (u64*)(out + (size_t)row * D2) + lane);
}

extern "C" void kernel_launch(void* const* d_in, const int* in_sizes, int n_in,
                              void* d_out, int out_size, void* d_ws, size_t ws_size,
                              hipStream_t stream) {
    const float* x    = (const float*)d_in[0];
    const int*   erow = (const int*)  d_in[1];
    const int*   ecol = (const int*)  d_in[2];
    const float* ew   = (const float*)d_in[3];
    const float* W1   = (const float*)d_in[4];
    const float* b1   = (const float*)d_in[5];
    const float* W2   = (const float*)d_in[6];
    const float* b2   = (const float*)d_in[7];
    float* out = (float*)d_out;

    // workspace layout (~49 MB, no aliasing):
    //   cnt[N int]  bcur[512 u32]  eg[N*CAP u32]  Bsw1[32768 u16]  Bsw2[4096 u16]
    //   s1b[4 planes x N*32 u16]  hb[N*128 u16]  s2b[N*32 u16]  ebuf[NB*BCAP u64]
    int* cnt   = (int*)d_ws;
    u32* bcur  = (u32*)(cnt + N_NODES);
    u32* eg    = (u32*)(bcur + 512);
    u16* Bsw1  = (u16*)(eg + (size_t)N_NODES * CAP);
    u16* Bsw2  = Bsw1 + 8 * 8 * 64 * 8;
    u16* s1b   = Bsw2 + 4 * 2 * 64 * 8;
    u16* hb    = s1b + NSL * PL;
    u16* s2b   = hb + (size_t)N_NODES * D1;
    u64* ebuf  = (u64*)(s2b + (size_t)N_NODES * D2);

    hipMemsetAsync(bcur, 0, 512 * sizeof(u32), stream);
    // k1: bucket-sort phase 1 (scatter) | W1 swizzle | W2 swizzle
    scatter_kernel<<<SC_BLOCKS + SW_BLOCKS + 1, 1024, 0, stream>>>(
        erow, ecol, ew, bcur, ebuf, W1, Bsw1, W2, Bsw2);
    // k2: bucket-sort phase 2 | gemm1 (4-plane slice-major s1b)
    gb_kernel<<<NB + G1_BLOCKS, 256, 0, stream>>>(x, Bsw1, s1b, bcur, ebuf, cnt, eg);
    // k3: XCD-sliced layer-1 aggregate (4 slices x 32 feats; 3.2MB L2-resident plane)
    spmm1_slice_kernel<<<RG_BLOCKS * NSL, dim3(8, 32), 0, stream>>>(cnt, eg, s1b, b1, hb);
    // k4: layer-2 dense projection (MFMA)
    gemm2_mfma_kernel<<<(N_NODES + 63) / 64, 256, 0, stream>>>(hb, Bsw2, s2b);
    // k5: layer-2 aggregate
    spmm_csr32_kernel<<<(N_NODES + 15) / 16, dim3(16, 16), 0, stream>>>(cnt, eg, s2b, b2, out);
}